// Round 1
// baseline (67.276 us; speedup 1.0000x reference)
//
#include <hip/hip_runtime.h>
#include <math.h>

// x: [512,64,64,1] f32, conv_w: [3,3,1,32] f32, conv_b: [32],
// dense_w: [32,10], dense_b: [10]; out: [512,10] f32 softmax.
//
// Algebraic collapse (verified, absmax==0 in prior round): conv -> global
// mean pool needs only 9 shifted-window sums per image, derivable from
// total T, edge-row sums Rt/Rb, edge-col sums Cl/Cr, and 4 corners.
// logits[b,j] = (1/4096) * sum_k S[b,k] * M[k,j] + bias[j]
//   M[k,j]  = sum_c sign(conv_w[k,c]) * dense_w[c,j]       (9x10)
//   bias[j] = sum_c conv_b[c]*dense_w[c,j] + dense_b[j]
//
// This version: ONE WAVE per image (64 thr x 512 blocks).
//  - 16 coalesced float4 loads issued up-front (16x MLP/lane).
//  - M/bias fold spread over all 64 lanes (100 tasks, <=2/lane),
//    latency-hidden under the image loads; exchanged via 400 B LDS.
//  - single 64-lane butterfly; lane-parallel tail (lane j owns logit j).

__global__ __launch_bounds__(64) void binconv_fused(
    const float* __restrict__ x,
    const float* __restrict__ conv_w,
    const float* __restrict__ conv_b,
    const float* __restrict__ dense_w,
    const float* __restrict__ dense_b,
    float* __restrict__ out)
{
    const int b = blockIdx.x;
    const int t = threadIdx.x;                 // 0..63, one wave
    const float4* img4 = (const float4*)(x + (size_t)b * 4096);

    // ---- issue all image loads first (wave covers contiguous 1 KiB per k)
    float4 v[16];
#pragma unroll
    for (int k = 0; k < 16; ++k) v[k] = img4[k * 64 + t];

    // ---- fold M + bias across all 64 lanes while loads are in flight.
    // tasks 0..89: M[k][j] (k=t/10, j=t%10); tasks 90..99: bias[j].
    __shared__ float MB[100];
    {
        const int t0 = t;              // always < 100
        float r0 = 0.f;
        if (t0 < 90) {
            const int k = t0 / 10, j = t0 % 10;
#pragma unroll 8
            for (int c = 0; c < 32; ++c) {
                const float dw = dense_w[c * 10 + j];
                r0 += (conv_w[k * 32 + c] >= 0.f) ? dw : -dw;  // ste_sign(0)=+1
            }
        } else {
            const int j = t0 - 90;
            r0 = dense_b[j];
#pragma unroll 8
            for (int c = 0; c < 32; ++c) r0 += conv_b[c] * dense_w[c * 10 + j];
        }
        MB[t0] = r0;

        const int t1 = t + 64;
        if (t1 < 100) {
            float r1 = 0.f;
            if (t1 < 90) {
                const int k = t1 / 10, j = t1 % 10;
#pragma unroll 8
                for (int c = 0; c < 32; ++c) {
                    const float dw = dense_w[c * 10 + j];
                    r1 += (conv_w[k * 32 + c] >= 0.f) ? dw : -dw;
                }
            } else {
                const int j = t1 - 90;
                r1 = dense_b[j];
#pragma unroll 8
                for (int c = 0; c < 32; ++c) r1 += conv_b[c] * dense_w[c * 10 + j];
            }
            MB[t1] = r1;
        }
    }

    // ---- per-thread partials. float4 index i = k*64+t:
    //      row = k*4 + (t>>4); starting col = (t&15)*4 (thread-constant).
    float tot = 0.f, top = 0.f, bot = 0.f, lef = 0.f, rig = 0.f;
    const int cg = t & 15;
    const int rg = t >> 4;
#pragma unroll
    for (int k = 0; k < 16; ++k) {
        const float4 vv = v[k];
        const float s4 = (vv.x + vv.y) + (vv.z + vv.w);
        tot += s4;
        if (k == 0 && rg == 0)  top += s4;   // row 0
        if (k == 15 && rg == 3) bot += s4;   // row 63
        if (cg == 0)  lef += vv.x;           // col 0
        if (cg == 15) rig += vv.w;           // col 63
    }
    float corn = 0.f;
    if (t == 0)  corn = v[0].x;    // x[0][0]
    if (t == 15) corn = v[0].w;    // x[0][63]
    if (t == 48) corn = v[15].x;   // x[63][0]
    if (t == 63) corn = v[15].w;   // x[63][63]

    // ---- single 64-lane butterfly for the 5 sums
#pragma unroll
    for (int off = 32; off; off >>= 1) {
        tot += __shfl_xor(tot, off);
        top += __shfl_xor(top, off);
        bot += __shfl_xor(bot, off);
        lef += __shfl_xor(lef, off);
        rig += __shfl_xor(rig, off);
    }
    const float x00 = __shfl(corn, 0);
    const float x0e = __shfl(corn, 15);
    const float xe0 = __shfl(corn, 48);
    const float xee = __shfl(corn, 63);

    __syncthreads();   // MB writes -> reads (single wave: just a waitcnt)

    // ---- window sums (identical algebra to the verified kernel)
    float S[9];
#pragma unroll
    for (int dh = 0; dh < 3; ++dh) {
#pragma unroll
        for (int dw = 0; dw < 3; ++dw) {
            float s = tot;
            if (dh == 0) s -= bot;           // drop row 63
            if (dh == 2) s -= top;           // drop row 0
            if (dw == 0) s -= rig;           // drop col 63
            if (dw == 2) s -= lef;           // drop col 0
            if (dh == 0 && dw == 0) s += xee;
            if (dh == 0 && dw == 2) s += xe0;
            if (dh == 2 && dw == 0) s += x0e;
            if (dh == 2 && dw == 2) s += x00;
            S[dh * 3 + dw] = s;
        }
    }

    // ---- lane-parallel tail: lane j (<10) owns logit j. Lanes 10..15 carry
    //      -1e30 so the 16-wide butterflies reduce exactly logits 0..9.
    float m[9], bs;
    if (t < 10) {
#pragma unroll
        for (int k = 0; k < 9; ++k) m[k] = MB[k * 10 + t];
        bs = MB[90 + t];
    } else {
#pragma unroll
        for (int k = 0; k < 9; ++k) m[k] = 0.f;
        bs = -1e30f;
    }
    float acc = 0.f;
#pragma unroll
    for (int k = 0; k < 9; ++k) acc += S[k] * m[k];
    const float logit = acc * (1.f / 4096.f) + bs;

    float mx = logit;
#pragma unroll
    for (int off = 8; off; off >>= 1) mx = fmaxf(mx, __shfl_xor(mx, off));
    const float ex = expf(logit - mx);       // lanes>=10: exp(-huge) = 0
    float se = ex;
#pragma unroll
    for (int off = 8; off; off >>= 1) se += __shfl_xor(se, off);
    const float inv = 1.f / se;
    if (t < 10) out[b * 10 + t] = ex * inv;
}

extern "C" void kernel_launch(void* const* d_in, const int* in_sizes, int n_in,
                              void* d_out, int out_size, void* d_ws, size_t ws_size,
                              hipStream_t stream) {
    const float* x       = (const float*)d_in[0];
    const float* conv_w  = (const float*)d_in[1];
    const float* conv_b  = (const float*)d_in[2];
    const float* dense_w = (const float*)d_in[3];
    const float* dense_b = (const float*)d_in[4];
    float* out = (float*)d_out;
    binconv_fused<<<512, 64, 0, stream>>>(x, conv_w, conv_b, dense_w, dense_b, out);
}